// Round 4
// baseline (688.600 us; speedup 1.0000x reference)
//
#include <hip/hip_runtime.h>
#include <hip/hip_cooperative_groups.h>
#include <math.h>

namespace cg = cooperative_groups;

#define BB 32
#define PP 2048
#define CC 512
#define TT 128              // PP/16
#define PLANES (BB*TT)      // 4096 t-planes, 16 rows x 512 ch each
#define PPB 4               // planes per block
#define NBLK (PLANES/PPB)   // 1024 blocks
#define THR 512

// Single cooperative kernel, two streaming passes over x.
// Pass A: pure read stream -> per-row channel means (no payload holding).
// grid.sync()
// Pass B/C: gates from cached means, then re-read x (L3-warm) * gate -> out.
// Thread map: row = tid>>3 (64 rows = 4 planes x 16), seg = tid&7;
// each thread streams 16 float4 at stride 8 (8-lane groups read 128 B
// contiguous chunks -> fully coalesced 1 KB per wave instruction).
__global__ __launch_bounds__(THR, 8) void coop_kernel(
        const float* __restrict__ x,
        const float* __restrict__ w1, const float* __restrict__ w2,
        const float* __restrict__ w3, float* __restrict__ out,
        float* __restrict__ wsmean) {
    __shared__ float sm[6][16];    // means of planes t0-1 .. t0+4
    __shared__ float sgate[64];    // gates for the block's 64 rows

    // XCD-chunked bijective swizzle (1024 = 8 XCD x 128): adjacent chunks
    // (same b, adjacent t0) share an XCD -> mean reads are L2-local.
    int bid = blockIdx.x;
    int wg  = ((bid & 7) << 7) | (bid >> 3);
    int b   = wg >> 5;             // 32 chunks of 4 planes per b
    int t0  = (wg & 31) << 2;
    int plane0 = b * TT + t0;

    int tid = threadIdx.x;
    int row = tid >> 3;            // 0..63: plane q = row>>4, r = row&15
    int seg = tid & 7;

    const float4* xr = (const float4*)x + (size_t)plane0 * 2048 + row * 128;

    // ---- pass A: read + reduce, 16 independent loads, 4 acc chains ----
    float a0 = 0.f, a1 = 0.f, a2 = 0.f, a3 = 0.f;
    #pragma unroll
    for (int k = 0; k < 4; ++k) {
        float4 u = xr[seg + 8 * (4 * k + 0)];
        float4 v = xr[seg + 8 * (4 * k + 1)];
        float4 p = xr[seg + 8 * (4 * k + 2)];
        float4 q = xr[seg + 8 * (4 * k + 3)];
        a0 += (u.x + u.y) + (u.z + u.w);
        a1 += (v.x + v.y) + (v.z + v.w);
        a2 += (p.x + p.y) + (p.z + p.w);
        a3 += (q.x + q.y) + (q.z + q.w);
    }
    float s = (a0 + a1) + (a2 + a3);
    s += __shfl_xor(s, 1, 64);
    s += __shfl_xor(s, 2, 64);
    s += __shfl_xor(s, 4, 64);
    if (seg == 0) wsmean[plane0 * 16 + row] = s * (1.0f / 512.0f);

    __threadfence();
    cg::this_grid().sync();

    // ---- pass B: 64 gates from cached means ----
    if (tid < 96) {
        int q = tid >> 4;          // 0..5 -> plane t0+q-1
        int r = tid & 15;
        int tq = t0 + q - 1;
        sm[q][r] = (tq >= 0 && tq < TT) ? wsmean[(b * TT + tq) * 16 + r] : 0.0f;
    }
    __syncthreads();
    if (tid < 64) {
        int q  = tid >> 4;         // plane t0+q
        int r  = tid & 15;
        int h  = r >> 2;
        int w_ = r & 3;
        float g = 0.0f;
        #pragma unroll
        for (int i = 0; i < 3; ++i) {
            #pragma unroll
            for (int j = 0; j < 3; ++j) {
                int hh = h + j - 1;
                if (hh < 0 || hh > 3) continue;
                #pragma unroll
                for (int k = 0; k < 3; ++k) {
                    int ww = w_ + k - 1;
                    if (ww < 0 || ww > 3) continue;
                    float wt = w3[i * 9 + j * 3 + k];
                    if (i < 2 && j < 2 && k < 2) wt += w2[i * 4 + j * 2 + k];
                    if (i == 1 && j == 1 && k == 1) wt += w1[0];
                    g += wt * sm[q + i][hh * 4 + ww];   // sm[m] = plane t0+m-1
                }
            }
        }
        sgate[tid] = 1.0f / (1.0f + __expf(-g));
    }
    __syncthreads();

    // ---- pass C: re-read (L3-warm) -> scale -> store; one gate/thread ----
    float g = sgate[row];
    float4* op = (float4*)out + (size_t)plane0 * 2048 + row * 128;
    #pragma unroll
    for (int k = 0; k < 16; ++k) {
        float4 v = xr[seg + 8 * k];
        v.x *= g; v.y *= g; v.z *= g; v.w *= g;
        op[seg + 8 * k] = v;
    }
}

// ---------------- fallback (non-cooperative split), known-good ----------------
__global__ __launch_bounds__(256) void mean_fb(
        const float* __restrict__ x, float* __restrict__ mean) {
    __shared__ float spart[4][8];
    int bid = blockIdx.x, tid = threadIdx.x;
    int wave = tid >> 6, lane = tid & 63;
    const float4* xt = (const float4*)x + (size_t)bid * 2048;
    float p[8];
    #pragma unroll
    for (int j = 0; j < 8; ++j) {
        float4 v = xt[tid + 256 * j];
        p[j] = (v.x + v.y) + (v.z + v.w);
    }
    #pragma unroll
    for (int j = 0; j < 8; ++j) {
        float s = p[j];
        #pragma unroll
        for (int off = 32; off > 0; off >>= 1) s += __shfl_down(s, off, 64);
        if (lane == 0) spart[wave][j] = s;
    }
    __syncthreads();
    if (tid < 16) {
        int jj = tid >> 1;
        float s = (tid & 1) ? (spart[2][jj] + spart[3][jj])
                            : (spart[0][jj] + spart[1][jj]);
        mean[bid * 16 + tid] = s * (1.0f / 512.0f);
    }
}

__global__ __launch_bounds__(256) void gate_scale_fb(
        const float* __restrict__ x, const float* __restrict__ mean,
        const float* __restrict__ w1, const float* __restrict__ w2,
        const float* __restrict__ w3, float* __restrict__ out) {
    __shared__ float sm[3][16];
    __shared__ float sgate[16];
    int bid = blockIdx.x;
    int b = bid >> 7, t = bid & 127, tid = threadIdx.x;
    if (tid < 48) {
        int plane = tid >> 4, r = tid & 15, tv = t + plane - 1;
        sm[plane][r] = (tv >= 0 && tv < TT) ? mean[(b * TT + tv) * 16 + r] : 0.0f;
    }
    __syncthreads();
    if (tid < 16) {
        int h = tid >> 2, w_ = tid & 3;
        float g = 0.0f;
        #pragma unroll
        for (int i = 0; i < 3; ++i)
            #pragma unroll
            for (int j = 0; j < 3; ++j) {
                int hh = h + j - 1;
                if (hh < 0 || hh > 3) continue;
                #pragma unroll
                for (int k = 0; k < 3; ++k) {
                    int ww = w_ + k - 1;
                    if (ww < 0 || ww > 3) continue;
                    float wt = w3[i * 9 + j * 3 + k];
                    if (i < 2 && j < 2 && k < 2) wt += w2[i * 4 + j * 2 + k];
                    if (i == 1 && j == 1 && k == 1) wt += w1[0];
                    g += wt * sm[i][hh * 4 + ww];
                }
            }
        sgate[tid] = 1.0f / (1.0f + __expf(-g));
    }
    __syncthreads();
    const float4* xt = (const float4*)x + (size_t)bid * 2048;
    float4*       ot = (float4*)out     + (size_t)bid * 2048;
    #pragma unroll
    for (int j = 0; j < 8; ++j) {
        int idx = tid + 256 * j;
        float s = sgate[idx >> 7];
        float4 v = xt[idx];
        v.x *= s; v.y *= s; v.z *= s; v.w *= s;
        ot[idx] = v;
    }
}

extern "C" void kernel_launch(void* const* d_in, const int* in_sizes, int n_in,
                              void* d_out, int out_size, void* d_ws, size_t ws_size,
                              hipStream_t stream) {
    const float* x  = (const float*)d_in[0];
    const float* w1 = (const float*)d_in[1];
    const float* w2 = (const float*)d_in[2];
    const float* w3 = (const float*)d_in[3];
    float* out  = (float*)d_out;
    float* mean = (float*)d_ws;           // 65536 floats

    void* args[] = {(void*)&x, (void*)&w1, (void*)&w2, (void*)&w3,
                    (void*)&out, (void*)&mean};
    hipError_t err = hipLaunchCooperativeKernel(
        (const void*)coop_kernel, dim3(NBLK), dim3(THR), args, 0, stream);
    if (err != hipSuccess) {
        // fallback: non-cooperative two-kernel path
        mean_fb<<<PLANES, 256, 0, stream>>>(x, mean);
        gate_scale_fb<<<PLANES, 256, 0, stream>>>(x, mean, w1, w2, w3, out);
    }
}

// Round 5
// 241.796 us; speedup vs baseline: 2.8479x; 2.8479x over previous
//
#include <hip/hip_runtime.h>
#include <math.h>

#define BB 32
#define PP 2048
#define CC 512
#define TT 128              // PP/16
#define TC 4                // t-planes per block
#define NBLK (BB*TT/TC)     // 1024 blocks
#define THR 512

// Fused mean + 27-tap gate + sigmoid + scale. One block per (b, 4-plane
// chunk). Own 4 planes (128 KB) held in registers (16 float4/thread,
// PINNED via empty asm so the compiler cannot sink the loads past the
// barrier and re-read — the r3 failure). Halo = planes t0-1, t0+4 only:
// read amplification 1.5x vs r1's 3x. Total fabric bytes ~335 MB.
__global__ __launch_bounds__(THR, 4) void fused4_kernel(
        const float* __restrict__ x,
        const float* __restrict__ w1, const float* __restrict__ w2,
        const float* __restrict__ w3, float* __restrict__ out) {
    __shared__ float sm[6][16];    // means of planes t0-1 .. t0+4
    __shared__ float sgate[64];    // gates for the block's 64 rows

    // XCD-chunked bijective swizzle: 1024 = 8 XCD x 128. Adjacent chunks
    // (same b, adjacent t0, sharing halo planes) land on the same XCD.
    int bid = blockIdx.x;
    int wg  = ((bid & 7) << 7) | (bid >> 3);
    int b   = wg >> 5;             // 32 chunks per b
    int t0  = (wg & 31) << 2;
    int plane0 = b * TT + t0;

    int tid = threadIdx.x;
    int row = tid >> 3;            // 0..63 (plane q = row>>4, r = row&15)
    int seg = tid & 7;

    const float4* xb = (const float4*)x + (size_t)b * (PP * CC / 4);
    const float4* xr = (const float4*)x + (size_t)plane0 * 2048 + row * 128;

    // ---- own 4 planes: 16 coalesced float4/thread, to be held ----
    float4 v[16];
    #pragma unroll
    for (int k = 0; k < 16; ++k) v[k] = xr[seg + 8 * k];

    // ---- halo planes t0-1 / t0+4: 32 rows, 16 thr/row, 8 f4/thread ----
    int hr2    = tid >> 4;         // 0..31
    int hseg   = tid & 15;
    int hplane = hr2 >> 4;         // 0 -> t0-1, 1 -> t0+4
    int hrw    = hr2 & 15;
    int ht     = hplane ? (t0 + TC) : (t0 - 1);
    bool hv    = (ht >= 0) && (ht < TT);
    float hs = 0.0f;
    if (hv) {
        const float4* hp = xb + (size_t)ht * 2048 + hrw * 128;
        float ha = 0.f, hb2 = 0.f;
        #pragma unroll
        for (int k = 0; k < 4; ++k) {
            float4 u = hp[hseg + 16 * (2 * k)];
            float4 w = hp[hseg + 16 * (2 * k + 1)];
            ha  += (u.x + u.y) + (u.z + u.w);
            hb2 += (w.x + w.y) + (w.z + w.w);
        }
        hs = ha + hb2;
    }

    // ---- own-row sum: 4 chains, then 3-step xor over the 8 segs ----
    float a0 = 0.f, a1 = 0.f, a2 = 0.f, a3 = 0.f;
    #pragma unroll
    for (int k = 0; k < 4; ++k) {
        a0 += (v[4*k+0].x + v[4*k+0].y) + (v[4*k+0].z + v[4*k+0].w);
        a1 += (v[4*k+1].x + v[4*k+1].y) + (v[4*k+1].z + v[4*k+1].w);
        a2 += (v[4*k+2].x + v[4*k+2].y) + (v[4*k+2].z + v[4*k+2].w);
        a3 += (v[4*k+3].x + v[4*k+3].y) + (v[4*k+3].z + v[4*k+3].w);
    }
    float s = (a0 + a1) + (a2 + a3);

    // ---- PIN the payload: compiler must keep v[] in VGPRs from here ----
    #pragma unroll
    for (int k = 0; k < 16; ++k)
        asm volatile("" : "+v"(v[k].x), "+v"(v[k].y), "+v"(v[k].z), "+v"(v[k].w));

    s += __shfl_xor(s, 1, 64);
    s += __shfl_xor(s, 2, 64);
    s += __shfl_xor(s, 4, 64);

    hs += __shfl_xor(hs, 1, 64);
    hs += __shfl_xor(hs, 2, 64);
    hs += __shfl_xor(hs, 4, 64);
    hs += __shfl_xor(hs, 8, 64);

    if (seg == 0)  sm[1 + (row >> 4)][row & 15] = s * (1.0f / 512.0f);
    if (hseg == 0) sm[hplane ? 5 : 0][hrw] = hv ? hs * (1.0f / 512.0f) : 0.0f;
    __syncthreads();

    // ---- 64 gates: plane q = tid>>4 (t0+q), pos r = tid&15 ----
    if (tid < 64) {
        int q  = tid >> 4;
        int r  = tid & 15;
        int h  = r >> 2;
        int w_ = r & 3;
        float g = 0.0f;
        #pragma unroll
        for (int i = 0; i < 3; ++i) {
            #pragma unroll
            for (int j = 0; j < 3; ++j) {
                int hh = h + j - 1;
                if (hh < 0 || hh > 3) continue;
                #pragma unroll
                for (int k = 0; k < 3; ++k) {
                    int ww = w_ + k - 1;
                    if (ww < 0 || ww > 3) continue;
                    float wt = w3[i * 9 + j * 3 + k];
                    if (i < 2 && j < 2 && k < 2) wt += w2[i * 4 + j * 2 + k];
                    if (i == 1 && j == 1 && k == 1) wt += w1[0];
                    g += wt * sm[q + i][hh * 4 + ww];   // sm[m] = plane t0+m-1
                }
            }
        }
        sgate[tid] = 1.0f / (1.0f + __expf(-g));
    }
    __syncthreads();

    // ---- scale the held registers, coalesced store ----
    float g = sgate[row];
    float4* op = (float4*)out + (size_t)plane0 * 2048 + row * 128;
    #pragma unroll
    for (int k = 0; k < 16; ++k) {
        float4 o = v[k];
        o.x *= g; o.y *= g; o.z *= g; o.w *= g;
        op[seg + 8 * k] = o;
    }
}

extern "C" void kernel_launch(void* const* d_in, const int* in_sizes, int n_in,
                              void* d_out, int out_size, void* d_ws, size_t ws_size,
                              hipStream_t stream) {
    const float* x  = (const float*)d_in[0];
    const float* w1 = (const float*)d_in[1];
    const float* w2 = (const float*)d_in[2];
    const float* w3 = (const float*)d_in[3];
    float* out = (float*)d_out;

    fused4_kernel<<<NBLK, THR, 0, stream>>>(x, w1, w2, w3, out);
}